// Round 4
// baseline (217.270 us; speedup 1.0000x reference)
//
#include <hip/hip_runtime.h>

// out[b,c,i,j] = x[b,c,i,j] * (i%3!=0) * (j%3!=0)
// Unfold->fold composite == elementwise separable 0/1 mask (see prior rounds).
//
// R3 experiment: DENSE READ variant (H1-vs-H2 discriminator).
// Previous kernels skipped loading the 11/32 all-zero rows (222 MB total,
// hole-y read stream, wave-divergent branch). This version reads everything
// (268 MB total) with both streams perfectly dense and ZERO branches:
// the mask is applied with branchless selects (cndmask), identical work on
// every lane. If the 4.5 TB/s plateau was ragged-stream-induced (H1), this
// runs at copy BW (~6.3 TB/s) and wins despite +46 MB. If mixed r/w traffic
// just caps at ~4.5 TB/s (H2), this regresses and R1 was the floor.
//
// Structure: R1's best-measured layout — one float4 per thread, blocks sweep
// linearly, grid sized exactly. Non-temporal on both streams (poison fill
// evicts caches between iterations; zero reuse).

typedef float vf4 __attribute__((ext_vector_type(4)));

constexpr int N_TOTAL = 64 * 512 * 32 * 32;   // 33,554,432 floats
constexpr int N_F4    = N_TOTAL / 4;          // 8,388,608 float4s

__global__ __launch_bounds__(256) void unfoldfold_mask_kernel(
    const vf4* __restrict__ x, vf4* __restrict__ out) {
    int q = blockIdx.x * blockDim.x + threadIdx.x;   // float4 index; grid exact
    vf4 a = __builtin_nontemporal_load(&x[q]);

    int i = (q >> 3) & 31;            // row within 32x32 image
    int ri = i - (i / 3) * 3;         // i % 3 (compiler: magic mul)
    int m  = (q & 7);                 // col group; j0 = m*4, j0%3 == m%3
    m = m - (m / 3) * 3;

    // element e of the float4 is at column j0+e; zero iff (j0+e)%3==0
    //   e=0: m==0   e=1: m==2   e=2: m==1   e=3: m==0
    float row = (ri == 0) ? 0.f : 1.f;
    a.x *= (m == 0) ? 0.f : row;
    a.y *= (m == 2) ? 0.f : row;
    a.z *= (m == 1) ? 0.f : row;
    a.w *= (m == 0) ? 0.f : row;

    __builtin_nontemporal_store(a, &out[q]);
}

extern "C" void kernel_launch(void* const* d_in, const int* in_sizes, int n_in,
                              void* d_out, int out_size, void* d_ws, size_t ws_size,
                              hipStream_t stream) {
    const vf4* x = (const vf4*)d_in[0];
    vf4* out = (vf4*)d_out;
    unfoldfold_mask_kernel<<<N_F4 / 256, 256, 0, stream>>>(x, out);
}